// Round 4
// baseline (520.102 us; speedup 1.0000x reference)
//
#include <hip/hip_runtime.h>
#include <hip/hip_bf16.h>
#include <hip/hip_cooperative_groups.h>

namespace cg = cooperative_groups;

#define KK 9
#define PADK 4
#define CIN 64
#define COUT 64
#define LSEQ 131072
#define NB 4
#define TILEL 128         // 128 l >= 128 B wave row segment in bf16 out (R2 lesson)
#define XROWS 136         // TILEL + KK - 1
#define XRS 72            // xt row stride (bf16); 144 B rows -> uniform 8/bank reads
#define NTILES 1024       // LSEQ / TILEL
#define NPART 64
#define TPB 8             // tiles per block (fused kernel)
#define GRIDC (NB * NTILES / TPB)   // 512 blocks = 2/CU -> cooperative-safe

typedef __attribute__((ext_vector_type(8))) short v8s;
typedef __attribute__((ext_vector_type(4))) float v4f;

__device__ __forceinline__ unsigned short f2bf(float f) {
  __hip_bfloat16 h = __float2bfloat16(f);
  return *reinterpret_cast<unsigned short*>(&h);
}
__device__ __forceinline__ float bf2f(unsigned short s) {
  return __uint_as_float(((unsigned)s) << 16);
}

__device__ __forceinline__ void store_o(float* p, float v) { *p = v; }
__device__ __forceinline__ void store_o(__hip_bfloat16* p, float v) { *p = __float2bfloat16(v); }

// 16-lane (intra-row) sum on the VALU pipe via DPP (verified R2)
template <int CTRL>
__device__ __forceinline__ float dppadd(float v) {
  int s = __builtin_amdgcn_update_dpp(0, __float_as_int(v), CTRL, 0xF, 0xF, true);
  return v + __int_as_float(s);
}
__device__ __forceinline__ float red16(float v) {
  v = dppadd<0xB1>(v);
  v = dppadd<0x4E>(v);
  v = dppadd<0x141>(v);
  v = dppadd<0x140>(v);
  return v;
}

// ---------------------------------------------------------------------------
// Repack W[Cout][Cin][K] fp32 -> bf16 A-fragments for mfma_f32_16x16x32_bf16.
// ---------------------------------------------------------------------------
__global__ void wtrans_kernel(const float* __restrict__ W, v8s* __restrict__ Wt) {
  int t = blockIdx.x * 256 + threadIdx.x;
  if (t >= KK * 2 * 4 * 64) return;
  int lane = t & 63;
  int frag = t >> 6;
  int mblk = frag & 3;
  int s    = (frag >> 2) & 1;
  int k    = frag >> 3;
  int m = lane & 15, q = lane >> 4;
  int o = mblk * 16 + m;
  union { v8s v; unsigned short h[8]; } u;
#pragma unroll
  for (int j = 0; j < 8; ++j) {
    int c = 32 * s + q * 8 + j;
    u.h[j] = f2bf(W[(o * CIN + c) * KK + k]);
  }
  Wt[t] = u.v;
}

// ---------------------------------------------------------------------------
// R4 fused cooperative kernel (512 blocks, TPB=8).
// Phase A: R0 conv body + reg-prefetch of tile t+1 before a raw s_barrier
//          (lgkmcnt-only drain; global loads stay in flight under MFMA).
// grid.sync(); Phase B: per-block redundant BN finalize (32 KB stats, L2-hot)
//          + BN+ReLU apply over the 1024-l strip this block itself wrote.
// ---------------------------------------------------------------------------
template <typename OutT>
__global__ __launch_bounds__(256, 2)
void fused_kernel(const float* __restrict__ x, const float* __restrict__ coords,
                  const v8s* __restrict__ Wt, OutT* __restrict__ cv,
                  float* __restrict__ out,
                  float* __restrict__ stat_sum, float* __restrict__ stat_sq,
                  const float* __restrict__ gamma, const float* __restrict__ beta) {
  __shared__ __align__(16) __hip_bfloat16 xt[XROWS][XRS]; // 19584 B
  __shared__ float wt[KK][TILEL];                         //  4608 B (reused ph.B)

  const int tid  = threadIdx.x;
  const int wv   = tid >> 6;
  const int wo   = wv & 1;
  const int wl   = wv >> 1;
  const int lane = tid & 63;
  const int m = lane & 15;
  const int q = lane >> 4;

  const int bid = blockIdx.x;                 // 0..511
  const int b   = bid >> 7;                   // 128 blocks per batch
  const int t0  = (bid & 127) * TPB;          // 8 consecutive tiles
  const float* xb = x + (b * CIN) * LSEQ;
  const float* cb = coords + (b * 3) * LSEQ;
  OutT*  cvb  = cv  + (size_t)(b * COUT) * LSEQ;
  float* outb = out + (size_t)(b * COUT) * LSEQ;

  // staging roles
  const int cg8 = tid & 7, lc = tid >> 3, c8 = cg8 * 8;  // x main stage
  const int cn = tid & 127, kh = tid >> 7, k0 = kh * 4;  // coord k-half split

  // prefetch registers (live across the MFMA phase)
  float4 f[8];
  float4 hx;
  float sx, sy, sz;
  float nx[5], ny[5], nz[5];

  auto prefetch = [&](int tile) {
    const int l0 = tile * TILEL;
#pragma unroll
    for (int t = 0; t < 8; ++t)
      f[t] = *(const float4*)(xb + (c8 + t) * LSEQ + l0 + 4 * lc);
    if (tid < 128) {
      int side = tid >> 6, c = tid & 63;
      hx = make_float4(0.f, 0.f, 0.f, 0.f);
      if (side == 0) {
        if (tile != 0) hx = *(const float4*)(xb + c * LSEQ + l0 - 4);
      } else {
        if (tile != NTILES - 1) hx = *(const float4*)(xb + c * LSEQ + l0 + TILEL);
      }
    }
    sx = cb[l0 + cn];
    sy = cb[LSEQ + l0 + cn];
    sz = cb[2 * LSEQ + l0 + cn];
#pragma unroll
    for (int i = 0; i < 5; ++i) {
      int l = l0 + cn + (k0 + i) - PADK;
      float cx = 0.f, cy = 0.f, cz = 0.f;
      if ((unsigned)l < (unsigned)LSEQ) {     // zero-pad like jnp.pad
        cx = cb[l]; cy = cb[LSEQ + l]; cz = cb[2 * LSEQ + l];
      }
      nx[i] = cx; ny[i] = cy; nz[i] = cz;
    }
  };

  prefetch(t0);

#pragma unroll 1
  for (int ti = 0; ti < TPB; ++ti) {
    const int tile = t0 + ti;
    const int l0 = tile * TILEL;

    // ---- consume prefetched regs -> LDS ----
    {
      const float* fp = (const float*)&f[0];
#pragma unroll
      for (int j = 0; j < 4; ++j) {
        union { v8s v; unsigned short h[8]; } u;
#pragma unroll
        for (int t = 0; t < 8; ++t) u.h[t] = f2bf(fp[4 * t + j]);
        *(v8s*)&xt[4 + 4 * lc + j][c8] = u.v;
      }
      if (tid < 128) {
        int side = tid >> 6, c = tid & 63;
        int rb = side ? (TILEL + PADK) : 0;
        xt[rb + 0][c] = __float2bfloat16(hx.x);
        xt[rb + 1][c] = __float2bfloat16(hx.y);
        xt[rb + 2][c] = __float2bfloat16(hx.z);
        xt[rb + 3][c] = __float2bfloat16(hx.w);
      }
      float w5[5];
#pragma unroll
      for (int i = 0; i < 5; ++i) {
        float dx = nx[i] - sx, dy = ny[i] - sy, dz = nz[i] - sz;
        w5[i] = __expf(-0.5f * (dx * dx + dy * dy + dz * dz));
      }
      if (kh == 0) {
#pragma unroll
        for (int i = 0; i < 4; ++i) wt[i][cn] = w5[i] - w5[i + 1];
      } else {
#pragma unroll
        for (int i = 0; i < 4; ++i) wt[4 + i][cn] = w5[i] - w5[i + 1];
        wt[8][cn] = w5[4];
      }
    }

    // ---- issue next tile's loads; in flight across the raw barrier ----
    if (ti + 1 < TPB) prefetch(tile + 1);

    asm volatile("s_waitcnt lgkmcnt(0)" ::: "memory");
    __builtin_amdgcn_s_barrier();

    // ---- MFMA main loop (R0 body) ----
    v4f y[2][4], tot[2][4];
#pragma unroll
    for (int i = 0; i < 2; ++i)
#pragma unroll
      for (int j = 0; j < 4; ++j) {
        y[i][j]   = (v4f){0.f, 0.f, 0.f, 0.f};
        tot[i][j] = (v4f){0.f, 0.f, 0.f, 0.f};
      }

    const v8s* wp = Wt + (wo * 2) * 64 + lane;

#pragma unroll 1
    for (int k = 0; k < KK; ++k) {
#pragma unroll
      for (int s = 0; s < 2; ++s) {
        v8s a0 = wp[k * 512 + s * 256];
        v8s a1 = wp[k * 512 + s * 256 + 64];
#pragma unroll
        for (int nbq = 0; nbq < 4; ++nbq) {
          v8s bf = *(const v8s*)&xt[wl * 64 + nbq * 16 + m + k][q * 8 + 32 * s];
          y[0][nbq] = __builtin_amdgcn_mfma_f32_16x16x32_bf16(a0, bf, y[0][nbq], 0, 0, 0);
          y[1][nbq] = __builtin_amdgcn_mfma_f32_16x16x32_bf16(a1, bf, y[1][nbq], 0, 0, 0);
        }
      }
#pragma unroll
      for (int nbq = 0; nbq < 4; ++nbq) {
        float d = wt[k][wl * 64 + nbq * 16 + m];
#pragma unroll
        for (int mb = 0; mb < 2; ++mb)
#pragma unroll
          for (int r = 0; r < 4; ++r)
            tot[mb][nbq][r] = __builtin_fmaf(d, y[mb][nbq][r], tot[mb][nbq][r]);
      }
    }

    // ---- epilogue ----
    const int part = tile & (NPART - 1);
#pragma unroll
    for (int mb = 0; mb < 2; ++mb) {
#pragma unroll
      for (int r = 0; r < 4; ++r) {
        int o = wo * 32 + mb * 16 + q * 4 + r;
        float s1 = 0.f, s2 = 0.f;
#pragma unroll
        for (int nbq = 0; nbq < 4; ++nbq) {
          float v = tot[mb][nbq][r];
          s1 += v;
          s2 += v * v;
          store_o(&cvb[o * LSEQ + l0 + wl * 64 + nbq * 16 + m], v);
        }
        s1 = red16(s1);
        s2 = red16(s2);
        if (m == 0) {
          atomicAdd(&stat_sum[part * COUT + o], s1);
          atomicAdd(&stat_sq [part * COUT + o], s2);
        }
      }
    }

    __builtin_amdgcn_s_barrier();   // protect xt/wt before next iter's stage
  }

  // ---- grid-wide sync ----
  __threadfence();
  cg::this_grid().sync();

  // ---- Phase B: redundant per-block BN finalize + apply ----
  {
    float* wtf = &wt[0][0];
    const int o = tid & 63, pq = tid >> 6;
    float s1 = 0.f, s2 = 0.f;
#pragma unroll 4
    for (int p = pq * 16; p < pq * 16 + 16; ++p) {
      s1 += stat_sum[p * COUT + o];
      s2 += stat_sq [p * COUT + o];
    }
    wtf[128 + pq * 64 + o] = s1;
    wtf[384 + pq * 64 + o] = s2;
    __syncthreads();
    if (tid < 64) {
      float t1 = wtf[128 + tid] + wtf[192 + tid] + wtf[256 + tid] + wtf[320 + tid];
      float t2 = wtf[384 + tid] + wtf[448 + tid] + wtf[512 + tid] + wtf[576 + tid];
      const float invN = 1.0f / (float)(NB * LSEQ);
      float mean = t1 * invN;
      float var  = t2 * invN - mean * mean;   // biased, matches jnp.var
      float sc = gamma[tid] * rsqrtf(var + 1e-5f);
      wtf[tid]      = sc;
      wtf[64 + tid] = beta[tid] - mean * sc;
    }
    __syncthreads();

    // apply over this block's own 1024-l strip (hot in own XCD L2/L3)
    const int oo = tid >> 2, sg = tid & 3;
    const float sc = wtf[oo], sh = wtf[64 + oo];
    const size_t base = (size_t)oo * LSEQ + t0 * TILEL + sg * 256;
    if constexpr (sizeof(OutT) == 2) {
      const __hip_bfloat16* src = (const __hip_bfloat16*)cvb;
#pragma unroll 4
      for (int j = 0; j < 32; ++j) {
        union { v8s v; unsigned short h[8]; } u;
        u.v = *(const v8s*)(src + base + j * 8);
        float r[8];
#pragma unroll
        for (int i = 0; i < 8; ++i)
          r[i] = fmaxf(fmaf(bf2f(u.h[i]), sc, sh), 0.f);
        *(float4*)(outb + base + j * 8)     = make_float4(r[0], r[1], r[2], r[3]);
        *(float4*)(outb + base + j * 8 + 4) = make_float4(r[4], r[5], r[6], r[7]);
      }
    } else {
#pragma unroll 4
      for (int j = 0; j < 64; ++j) {
        float4 a = *(float4*)(outb + base + j * 4);
        a.x = fmaxf(fmaf(a.x, sc, sh), 0.f);
        a.y = fmaxf(fmaf(a.y, sc, sh), 0.f);
        a.z = fmaxf(fmaf(a.z, sc, sh), 0.f);
        a.w = fmaxf(fmaf(a.w, sc, sh), 0.f);
        *(float4*)(outb + base + j * 4) = a;
      }
    }
  }
}

// ---------------------------------------------------------------------------
// Fallback path: R0's proven trio (conv + finalize + scale), used only if the
// cooperative launch is rejected by the driver.
// ---------------------------------------------------------------------------
template <typename OutT>
__global__ __launch_bounds__(256, 4)
void conv_fallback(const float* __restrict__ x, const float* __restrict__ coords,
                   const v8s* __restrict__ Wt, OutT* __restrict__ cv,
                   float* __restrict__ stat_sum, float* __restrict__ stat_sq) {
  __shared__ __align__(16) __hip_bfloat16 xt[XROWS][XRS];
  __shared__ float wt[KK][TILEL];

  const int tid  = threadIdx.x;
  const int wv   = tid >> 6;
  const int wo   = wv & 1;
  const int wl   = wv >> 1;
  const int lane = tid & 63;
  const int gw   = blockIdx.x;
  const int b    = gw >> 10;
  const int tile = gw & (NTILES - 1);
  const int l0   = tile * TILEL;
  const float* xb = x + (b * CIN) * LSEQ;
  const float* cb = coords + (b * 3) * LSEQ;
  const int m = lane & 15;
  const int q = lane >> 4;

  {
    int cg = tid & 7;
    int lc = tid >> 3;
    int c8 = cg * 8;
    float4 f[8];
#pragma unroll
    for (int t = 0; t < 8; ++t)
      f[t] = *(const float4*)(xb + (c8 + t) * LSEQ + l0 + 4 * lc);
    const float* fp = (const float*)&f[0];
#pragma unroll
    for (int j = 0; j < 4; ++j) {
      union { v8s v; unsigned short h[8]; } u;
#pragma unroll
      for (int t = 0; t < 8; ++t) u.h[t] = f2bf(fp[4 * t + j]);
      *(v8s*)&xt[4 + 4 * lc + j][c8] = u.v;
    }
  }
  if (tid < 128) {
    int side = tid >> 6;
    int c = tid & 63;
    if (side == 0) {
      float el[4] = {0.f, 0.f, 0.f, 0.f};
      if (tile != 0) {
#pragma unroll
        for (int j = 0; j < 4; ++j) el[j] = xb[c * LSEQ + l0 - 4 + j];
      }
#pragma unroll
      for (int j = 0; j < 4; ++j) xt[j][c] = __float2bfloat16(el[j]);
    } else {
      float er[4] = {0.f, 0.f, 0.f, 0.f};
      if (tile != NTILES - 1) {
#pragma unroll
        for (int j = 0; j < 4; ++j) er[j] = xb[c * LSEQ + l0 + TILEL + j];
      }
#pragma unroll
      for (int j = 0; j < 4; ++j) xt[128 + 4 + j][c] = __float2bfloat16(er[j]);
    }
  }
  if (tid < TILEL) {
    int n = tid;
    float sx = cb[l0 + n];
    float sy = cb[LSEQ + l0 + n];
    float sz = cb[2 * LSEQ + l0 + n];
    float w9[KK];
#pragma unroll
    for (int k = 0; k < KK; ++k) {
      int l = l0 + n + k - PADK;
      float cx = 0.f, cy = 0.f, cz = 0.f;
      if ((unsigned)l < (unsigned)LSEQ) {
        cx = cb[l]; cy = cb[LSEQ + l]; cz = cb[2 * LSEQ + l];
      }
      float dx = cx - sx, dy = cy - sy, dz = cz - sz;
      w9[k] = __expf(-0.5f * (dx * dx + dy * dy + dz * dz));
    }
#pragma unroll
    for (int k = 0; k < KK; ++k)
      wt[k][n] = w9[k] - ((k < KK - 1) ? w9[k + 1] : 0.f);
  }
  __syncthreads();

  v4f y[2][4], tot[2][4];
#pragma unroll
  for (int i = 0; i < 2; ++i)
#pragma unroll
    for (int j = 0; j < 4; ++j) {
      y[i][j]   = (v4f){0.f, 0.f, 0.f, 0.f};
      tot[i][j] = (v4f){0.f, 0.f, 0.f, 0.f};
    }

  const v8s* wp = Wt + (wo * 2) * 64 + lane;

#pragma unroll 1
  for (int k = 0; k < KK; ++k) {
#pragma unroll
    for (int s = 0; s < 2; ++s) {
      v8s a0 = wp[k * 512 + s * 256];
      v8s a1 = wp[k * 512 + s * 256 + 64];
#pragma unroll
      for (int nbq = 0; nbq < 4; ++nbq) {
        v8s bf = *(const v8s*)&xt[wl * 64 + nbq * 16 + m + k][q * 8 + 32 * s];
        y[0][nbq] = __builtin_amdgcn_mfma_f32_16x16x32_bf16(a0, bf, y[0][nbq], 0, 0, 0);
        y[1][nbq] = __builtin_amdgcn_mfma_f32_16x16x32_bf16(a1, bf, y[1][nbq], 0, 0, 0);
      }
    }
#pragma unroll
    for (int nbq = 0; nbq < 4; ++nbq) {
      float d = wt[k][wl * 64 + nbq * 16 + m];
#pragma unroll
      for (int mb = 0; mb < 2; ++mb)
#pragma unroll
        for (int r = 0; r < 4; ++r)
          tot[mb][nbq][r] = __builtin_fmaf(d, y[mb][nbq][r], tot[mb][nbq][r]);
    }
  }

  const int part = gw & (NPART - 1);
  OutT* outb = cv + (size_t)(b * COUT) * LSEQ;
#pragma unroll
  for (int mb = 0; mb < 2; ++mb) {
#pragma unroll
    for (int r = 0; r < 4; ++r) {
      int o = wo * 32 + mb * 16 + q * 4 + r;
      float s1 = 0.f, s2 = 0.f;
#pragma unroll
      for (int nbq = 0; nbq < 4; ++nbq) {
        float v = tot[mb][nbq][r];
        s1 += v;
        s2 += v * v;
        store_o(&outb[o * LSEQ + l0 + wl * 64 + nbq * 16 + m], v);
      }
      s1 = red16(s1);
      s2 = red16(s2);
      if (m == 0) {
        atomicAdd(&stat_sum[part * COUT + o], s1);
        atomicAdd(&stat_sq [part * COUT + o], s2);
      }
    }
  }
}

__global__ void finalize_kernel(const float* __restrict__ stat_sum,
                                const float* __restrict__ stat_sq,
                                const float* __restrict__ gamma,
                                const float* __restrict__ beta,
                                float* __restrict__ ss) {
  int o = threadIdx.x;
  float s1 = 0.f, s2 = 0.f;
  for (int p = 0; p < NPART; ++p) {
    s1 += stat_sum[p * COUT + o];
    s2 += stat_sq [p * COUT + o];
  }
  const float invN = 1.0f / (float)(NB * LSEQ);
  float mean = s1 * invN;
  float var  = s2 * invN - mean * mean;
  float sc = gamma[o] * rsqrtf(var + 1e-5f);
  ss[o]        = sc;
  ss[COUT + o] = beta[o] - mean * sc;
}

__global__ __launch_bounds__(256)
void scale_f32_kernel(float* __restrict__ data, const float* __restrict__ ss) {
  const int blk = blockIdx.x;
  const int ch = (blk >> 6) & 63;
  const float sc = ss[ch];
  const float sh = ss[COUT + ch];
  const int base = blk * 2048 + threadIdx.x * 8;
  float4 a = *(float4*)(data + base);
  float4 b = *(float4*)(data + base + 4);
  a.x = fmaxf(fmaf(a.x, sc, sh), 0.f);
  a.y = fmaxf(fmaf(a.y, sc, sh), 0.f);
  a.z = fmaxf(fmaf(a.z, sc, sh), 0.f);
  a.w = fmaxf(fmaf(a.w, sc, sh), 0.f);
  b.x = fmaxf(fmaf(b.x, sc, sh), 0.f);
  b.y = fmaxf(fmaf(b.y, sc, sh), 0.f);
  b.z = fmaxf(fmaf(b.z, sc, sh), 0.f);
  b.w = fmaxf(fmaf(b.w, sc, sh), 0.f);
  *(float4*)(data + base)     = a;
  *(float4*)(data + base + 4) = b;
}

__global__ __launch_bounds__(256)
void scale_bf16_kernel(const __hip_bfloat16* __restrict__ cvin,
                       const float* __restrict__ ss, float* __restrict__ out) {
  const int blk = blockIdx.x;
  const int ch = (blk >> 6) & 63;
  const float sc = ss[ch];
  const float sh = ss[COUT + ch];
  const int base = blk * 2048 + threadIdx.x * 8;
  union { v8s v; unsigned short h[8]; } u;
  u.v = *(const v8s*)(cvin + base);
  float r[8];
#pragma unroll
  for (int i = 0; i < 8; ++i)
    r[i] = fmaxf(fmaf(bf2f(u.h[i]), sc, sh), 0.f);
  *(float4*)(out + base)     = make_float4(r[0], r[1], r[2], r[3]);
  *(float4*)(out + base + 4) = make_float4(r[4], r[5], r[6], r[7]);
}

extern "C" void kernel_launch(void* const* d_in, const int* in_sizes, int n_in,
                              void* d_out, int out_size, void* d_ws, size_t ws_size,
                              hipStream_t stream) {
  const float* x      = (const float*)d_in[0];
  const float* coords = (const float*)d_in[1];
  const float* W      = (const float*)d_in[2];
  // d_in[3] = bias: cancels under training-mode BatchNorm; unused.
  const float* gamma  = (const float*)d_in[4];
  const float* beta   = (const float*)d_in[5];
  float* out = (float*)d_out;
  char* ws = (char*)d_ws;

  float* stat_sum = (float*)(ws);            // 64*64 f32
  float* stat_sq  = (float*)(ws + 16384);    // 64*64 f32
  float* ss       = (float*)(ws + 32768);    // 128 f32
  v8s*   Wt       = (v8s*)(ws + 40960);      // 73728 B
  __hip_bfloat16* scratch = (__hip_bfloat16*)(ws + 131072); // 64 MiB (optional)

  const size_t need_bf16 = (size_t)131072 + (size_t)NB * COUT * LSEQ * 2;
  const bool bf16_path = ws_size >= need_bf16;

  hipMemsetAsync(ws, 0, 32768, stream);
  wtrans_kernel<<<18, 256, 0, stream>>>(W, Wt);

  hipError_t cerr;
  if (bf16_path) {
    void* args[9] = {(void*)&x, (void*)&coords, (void*)&Wt, (void*)&scratch,
                     (void*)&out, (void*)&stat_sum, (void*)&stat_sq,
                     (void*)&gamma, (void*)&beta};
    cerr = hipLaunchCooperativeKernel((void*)fused_kernel<__hip_bfloat16>,
                                      dim3(GRIDC), dim3(256), args, 0, stream);
    if (cerr != hipSuccess) {
      conv_fallback<__hip_bfloat16><<<NB * NTILES, 256, 0, stream>>>(
          x, coords, Wt, scratch, stat_sum, stat_sq);
      finalize_kernel<<<1, COUT, 0, stream>>>(stat_sum, stat_sq, gamma, beta, ss);
      scale_bf16_kernel<<<(NB * COUT * (LSEQ / 2048)), 256, 0, stream>>>(scratch, ss, out);
    }
  } else {
    float* cvf = out;   // conv writes f32 directly to out; apply in-place
    void* args[9] = {(void*)&x, (void*)&coords, (void*)&Wt, (void*)&cvf,
                     (void*)&out, (void*)&stat_sum, (void*)&stat_sq,
                     (void*)&gamma, (void*)&beta};
    cerr = hipLaunchCooperativeKernel((void*)fused_kernel<float>,
                                      dim3(GRIDC), dim3(256), args, 0, stream);
    if (cerr != hipSuccess) {
      conv_fallback<float><<<NB * NTILES, 256, 0, stream>>>(
          x, coords, Wt, out, stat_sum, stat_sq);
      finalize_kernel<<<1, COUT, 0, stream>>>(stat_sum, stat_sq, gamma, beta, ss);
      scale_f32_kernel<<<(NB * COUT * (LSEQ / 2048)), 256, 0, stream>>>(out, ss);
    }
  }
}

// Round 6
// 320.483 us; speedup vs baseline: 1.6229x; 1.6229x over previous
//
#include <hip/hip_runtime.h>
#include <hip/hip_bf16.h>

#define KK 9
#define PADK 4
#define CIN 64
#define COUT 64
#define LSEQ 131072
#define NB 4
#define TILEL 128         // l-extent of a block tile (>=128B wave row segment, R2 lesson)
#define XROWS 136         // TILEL + KK - 1
#define XRS 72            // xt row stride (bf16); 144 B rows -> uniform 8/bank reads
#define NTILES 1024       // LSEQ / TILEL
#define NPART 64

typedef __attribute__((ext_vector_type(8))) short v8s;
typedef __attribute__((ext_vector_type(4))) float v4f;

__device__ __forceinline__ unsigned short f2bf(float f) {
  __hip_bfloat16 h = __float2bfloat16(f);
  return *reinterpret_cast<unsigned short*>(&h);
}
__device__ __forceinline__ float bf2f(unsigned short s) {
  return __uint_as_float(((unsigned)s) << 16);
}

__device__ __forceinline__ void store_o(float* p, float v) { *p = v; }
__device__ __forceinline__ void store_o(__hip_bfloat16* p, float v) { *p = __float2bfloat16(v); }

// 16-lane (intra-row) sum on the VALU pipe via DPP (verified R2/R4)
template <int CTRL>
__device__ __forceinline__ float dppadd(float v) {
  int s = __builtin_amdgcn_update_dpp(0, __float_as_int(v), CTRL, 0xF, 0xF, true);
  return v + __int_as_float(s);
}
__device__ __forceinline__ float red16(float v) {
  v = dppadd<0xB1>(v);    // quad_perm xor1
  v = dppadd<0x4E>(v);    // quad_perm xor2
  v = dppadd<0x141>(v);   // row_half_mirror (xor 4)
  v = dppadd<0x140>(v);   // row_mirror (xor 8)
  return v;
}

// ---------------------------------------------------------------------------
// Repack W[Cout][Cin][K] fp32 -> bf16 A-fragments for mfma_f32_16x16x32_bf16,
// pre-swizzled: frag (k, s, mblk) is 1024 contiguous bytes, lane-major.
// ---------------------------------------------------------------------------
__global__ void wtrans_kernel(const float* __restrict__ W, v8s* __restrict__ Wt) {
  int t = blockIdx.x * 256 + threadIdx.x;
  if (t >= KK * 2 * 4 * 64) return;
  int lane = t & 63;
  int frag = t >> 6;
  int mblk = frag & 3;
  int s    = (frag >> 2) & 1;
  int k    = frag >> 3;
  int m = lane & 15, q = lane >> 4;
  int o = mblk * 16 + m;
  union { v8s v; unsigned short h[8]; } u;
#pragma unroll
  for (int j = 0; j < 8; ++j) {
    int c = 32 * s + q * 8 + j;
    u.h[j] = f2bf(W[(o * CIN + c) * KK + k]);
  }
  Wt[t] = u.v;
}

// ---------------------------------------------------------------------------
// Weighted conv via MFMA. R5: direct per-k accumulation (no telescope):
//   per (k,nbq): y4 = A(k,s1)*B1 + A(k,s0)*B0 (4-reg transient), tot += w_k*y4
// Same MFMA/LDS/FMA counts as the telescoped form but HALF the accumulator
// registers (tot 32 vs y+tot 64). Unified VGPR+AGPR ~96 -> 5 waves/EU
// (R0 was 52+64=116 -> 4/EU, measured 3.2 blocks/CU). Occupancy is the lever:
// per-tile throughput scaled ~linearly with resident blocks in R0/R1/R4.
// ---------------------------------------------------------------------------
template <typename OutT>
__global__ __launch_bounds__(256, 5)
void conv_kernel(const float* __restrict__ x, const float* __restrict__ coords,
                 const v8s* __restrict__ Wt, OutT* __restrict__ cv,
                 float* __restrict__ stat_sum, float* __restrict__ stat_sq) {
  __shared__ __align__(16) __hip_bfloat16 xt[XROWS][XRS]; // 19584 B
  __shared__ float wt[KK][TILEL];                         //  4608 B (raw w, not deltas)

  const int tid  = threadIdx.x;
  const int wv   = tid >> 6;
  const int wo   = wv & 1;                    // o-half (32 rows)
  const int wl   = wv >> 1;                   // l-half (64 cols)
  const int lane = tid & 63;
  const int gw   = blockIdx.x;                // tile id, 0..4095
  const int b    = gw >> 10;                  // / NTILES
  const int tile = gw & (NTILES - 1);
  const int l0   = tile * TILEL;
  const float* xb = x + (b * CIN) * LSEQ;
  const float* cb = coords + (b * 3) * LSEQ;
  const int m = lane & 15;
  const int q = lane >> 4;

  // ---- stage main x region (rows 4..131): lane-inner = channel-group so each
  //      b128 LDS write covers all 32 banks uniformly ----
  {
    int cg = tid & 7;                         // channel group (8 ch each)
    int lc = tid >> 3;                        // l-chunk 0..31 (4 l each)
    int c8 = cg * 8;
    float4 f[8];
#pragma unroll
    for (int t = 0; t < 8; ++t)
      f[t] = *(const float4*)(xb + (c8 + t) * LSEQ + l0 + 4 * lc);
    const float* fp = (const float*)&f[0];
#pragma unroll
    for (int j = 0; j < 4; ++j) {
      union { v8s v; unsigned short h[8]; } u;
#pragma unroll
      for (int t = 0; t < 8; ++t) u.h[t] = f2bf(fp[4 * t + j]);
      *(v8s*)&xt[4 + 4 * lc + j][c8] = u.v;
    }
  }
  // ---- halos (rows 0..3 and 132..135), zero-padded at sequence ends ----
  if (tid < 128) {
    int side = tid >> 6;
    int c = tid & 63;
    if (side == 0) {
      float el[4] = {0.f, 0.f, 0.f, 0.f};
      if (tile != 0) {
#pragma unroll
        for (int j = 0; j < 4; ++j) el[j] = xb[c * LSEQ + l0 - 4 + j];
      }
#pragma unroll
      for (int j = 0; j < 4; ++j) xt[j][c] = __float2bfloat16(el[j]);
    } else {
      float er[4] = {0.f, 0.f, 0.f, 0.f};
      if (tile != NTILES - 1) {
#pragma unroll
        for (int j = 0; j < 4; ++j) er[j] = xb[c * LSEQ + l0 + TILEL + j];
      }
#pragma unroll
      for (int j = 0; j < 4; ++j) xt[128 + 4 + j][c] = __float2bfloat16(er[j]);
    }
  }
  // ---- gaussian weights (raw; direct accumulation needs w_k, not deltas) ----
  if (tid < TILEL) {
    int n = tid;
    float sx = cb[l0 + n];
    float sy = cb[LSEQ + l0 + n];
    float sz = cb[2 * LSEQ + l0 + n];
#pragma unroll
    for (int k = 0; k < KK; ++k) {
      int l = l0 + n + k - PADK;
      float cx = 0.f, cy = 0.f, cz = 0.f;
      if ((unsigned)l < (unsigned)LSEQ) {     // zero-pad like jnp.pad
        cx = cb[l]; cy = cb[LSEQ + l]; cz = cb[2 * LSEQ + l];
      }
      float dx = cx - sx, dy = cy - sy, dz = cz - sz;
      wt[k][n] = __expf(-0.5f * (dx * dx + dy * dy + dz * dz));
    }
  }
  __syncthreads();

  // ---- MFMA main loop: direct per-k weighted accumulation ----
  v4f tot[2][4];
#pragma unroll
  for (int i = 0; i < 2; ++i)
#pragma unroll
    for (int j = 0; j < 4; ++j)
      tot[i][j] = (v4f){0.f, 0.f, 0.f, 0.f};

  const v4f z4 = (v4f){0.f, 0.f, 0.f, 0.f};
  // frag(k,s,mb) at Wt[k*512 + s*256 + mb*64 + lane]
  const v8s* wp = Wt + (wo * 2) * 64 + lane;

#pragma unroll 1
  for (int k = 0; k < KK; ++k) {
    v8s a00 = wp[k * 512];              // s=0, mb=0
    v8s a10 = wp[k * 512 + 64];         // s=0, mb=1
    v8s a01 = wp[k * 512 + 256];        // s=1, mb=0
    v8s a11 = wp[k * 512 + 256 + 64];   // s=1, mb=1
#pragma unroll
    for (int nbq = 0; nbq < 4; ++nbq) {
      const __hip_bfloat16* xr = &xt[wl * 64 + nbq * 16 + m + k][0];
      v8s bf0 = *(const v8s*)(xr + q * 8);
      v8s bf1 = *(const v8s*)(xr + q * 8 + 32);
      float wk = wt[k][wl * 64 + nbq * 16 + m];
      v4f y0 = __builtin_amdgcn_mfma_f32_16x16x32_bf16(a00, bf0, z4, 0, 0, 0);
      y0     = __builtin_amdgcn_mfma_f32_16x16x32_bf16(a01, bf1, y0, 0, 0, 0);
      v4f y1 = __builtin_amdgcn_mfma_f32_16x16x32_bf16(a10, bf0, z4, 0, 0, 0);
      y1     = __builtin_amdgcn_mfma_f32_16x16x32_bf16(a11, bf1, y1, 0, 0, 0);
#pragma unroll
      for (int r = 0; r < 4; ++r) {
        tot[0][nbq][r] = __builtin_fmaf(wk, y0[r], tot[0][nbq][r]);
        tot[1][nbq][r] = __builtin_fmaf(wk, y1[r], tot[1][nbq][r]);
      }
    }
  }

  // ---- epilogue: store conv result + per-channel sum/sumsq partials ----
  const int part = gw & (NPART - 1);
  OutT* outb = cv + (size_t)(b * COUT) * LSEQ;
#pragma unroll
  for (int mb = 0; mb < 2; ++mb) {
#pragma unroll
    for (int r = 0; r < 4; ++r) {
      int o = wo * 32 + mb * 16 + q * 4 + r;   // C-layout: row = q*4 + reg
      float s1 = 0.f, s2 = 0.f;
#pragma unroll
      for (int nbq = 0; nbq < 4; ++nbq) {
        float v = tot[mb][nbq][r];
        s1 += v;
        s2 += v * v;
        store_o(&outb[o * LSEQ + l0 + wl * 64 + nbq * 16 + m], v); // col = lane&15
      }
      s1 = red16(s1);                          // VALU-pipe DPP reduction
      s2 = red16(s2);
      if (m == 0) {
        atomicAdd(&stat_sum[part * COUT + o], s1);
        atomicAdd(&stat_sq [part * COUT + o], s2);
      }
    }
  }
}

// ---------------------------------------------------------------------------
// BN finalize: scale = gamma*rsqrt(var+eps), shift = beta - mean*scale.
// 256 threads (o x 4 part-quarters) instead of a 64-iter serial wave:
// cuts the latency-bound serial chain ~4x.
// ---------------------------------------------------------------------------
__global__ __launch_bounds__(256)
void finalize_kernel(const float* __restrict__ stat_sum,
                     const float* __restrict__ stat_sq,
                     const float* __restrict__ gamma,
                     const float* __restrict__ beta,
                     float* __restrict__ ss) {
  __shared__ float red[2][4][COUT];
  const int o = threadIdx.x & 63, pq = threadIdx.x >> 6;
  float s1 = 0.f, s2 = 0.f;
#pragma unroll 4
  for (int p = pq * 16; p < pq * 16 + 16; ++p) {
    s1 += stat_sum[p * COUT + o];
    s2 += stat_sq [p * COUT + o];
  }
  red[0][pq][o] = s1;
  red[1][pq][o] = s2;
  __syncthreads();
  if (threadIdx.x < 64) {
    float t1 = red[0][0][o] + red[0][1][o] + red[0][2][o] + red[0][3][o];
    float t2 = red[1][0][o] + red[1][1][o] + red[1][2][o] + red[1][3][o];
    const float invN = 1.0f / (float)(NB * LSEQ);
    float mean = t1 * invN;
    float var  = t2 * invN - mean * mean;   // biased, matches jnp.var
    float sc = gamma[o] * rsqrtf(var + 1e-5f);
    ss[o]        = sc;
    ss[COUT + o] = beta[o] - mean * sc;
  }
}

// ---- BN apply + ReLU; one block = 2048 contiguous elems in one channel ----
__global__ __launch_bounds__(256)
void scale_f32_kernel(float* __restrict__ data, const float* __restrict__ ss) {
  const int blk = blockIdx.x;
  const int ch = (blk >> 6) & 63;   // L/2048 = 64 blocks per channel
  const float sc = ss[ch];
  const float sh = ss[COUT + ch];
  const int base = blk * 2048 + threadIdx.x * 8;
  float4 a = *(float4*)(data + base);
  float4 b = *(float4*)(data + base + 4);
  a.x = fmaxf(fmaf(a.x, sc, sh), 0.f);
  a.y = fmaxf(fmaf(a.y, sc, sh), 0.f);
  a.z = fmaxf(fmaf(a.z, sc, sh), 0.f);
  a.w = fmaxf(fmaf(a.w, sc, sh), 0.f);
  b.x = fmaxf(fmaf(b.x, sc, sh), 0.f);
  b.y = fmaxf(fmaf(b.y, sc, sh), 0.f);
  b.z = fmaxf(fmaf(b.z, sc, sh), 0.f);
  b.w = fmaxf(fmaf(b.w, sc, sh), 0.f);
  *(float4*)(data + base)     = a;
  *(float4*)(data + base + 4) = b;
}

__global__ __launch_bounds__(256)
void scale_bf16_kernel(const __hip_bfloat16* __restrict__ cvin,
                       const float* __restrict__ ss, float* __restrict__ out) {
  const int blk = blockIdx.x;
  const int ch = (blk >> 6) & 63;
  const float sc = ss[ch];
  const float sh = ss[COUT + ch];
  const int base = blk * 2048 + threadIdx.x * 8;
  union { v8s v; unsigned short h[8]; } u;
  u.v = *(const v8s*)(cvin + base);
  float r[8];
#pragma unroll
  for (int i = 0; i < 8; ++i)
    r[i] = fmaxf(fmaf(bf2f(u.h[i]), sc, sh), 0.f);
  *(float4*)(out + base)     = make_float4(r[0], r[1], r[2], r[3]);
  *(float4*)(out + base + 4) = make_float4(r[4], r[5], r[6], r[7]);
}

extern "C" void kernel_launch(void* const* d_in, const int* in_sizes, int n_in,
                              void* d_out, int out_size, void* d_ws, size_t ws_size,
                              hipStream_t stream) {
  const float* x      = (const float*)d_in[0];
  const float* coords = (const float*)d_in[1];
  const float* W      = (const float*)d_in[2];
  // d_in[3] = bias: cancels under training-mode BatchNorm; unused.
  const float* gamma  = (const float*)d_in[4];
  const float* beta   = (const float*)d_in[5];
  float* out = (float*)d_out;
  char* ws = (char*)d_ws;

  float* stat_sum = (float*)(ws);            // 64*64 f32
  float* stat_sq  = (float*)(ws + 16384);    // 64*64 f32
  float* ss       = (float*)(ws + 32768);    // 128 f32
  v8s*   Wt       = (v8s*)(ws + 40960);      // 73728 B
  __hip_bfloat16* scratch = (__hip_bfloat16*)(ws + 131072); // 64 MiB (optional)

  const size_t need_bf16 = (size_t)131072 + (size_t)NB * COUT * LSEQ * 2;
  const bool bf16_path = ws_size >= need_bf16;

  hipMemsetAsync(ws, 0, 32768, stream);
  wtrans_kernel<<<18, 256, 0, stream>>>(W, Wt);

  if (bf16_path) {
    conv_kernel<__hip_bfloat16><<<NB * NTILES, 256, 0, stream>>>(
        x, coords, Wt, scratch, stat_sum, stat_sq);
    finalize_kernel<<<1, 256, 0, stream>>>(stat_sum, stat_sq, gamma, beta, ss);
    scale_bf16_kernel<<<(NB * COUT * (LSEQ / 2048)), 256, 0, stream>>>(scratch, ss, out);
  } else {
    conv_kernel<float><<<NB * NTILES, 256, 0, stream>>>(
        x, coords, Wt, out, stat_sum, stat_sq);
    finalize_kernel<<<1, 256, 0, stream>>>(stat_sum, stat_sq, gamma, beta, ss);
    scale_f32_kernel<<<(NB * COUT * (LSEQ / 2048)), 256, 0, stream>>>(out, ss);
  }
}